// Round 11
// baseline (295.211 us; speedup 1.0000x reference)
//
#include <hip/hip_runtime.h>
#include <hip/hip_bf16.h>

#define CAP 64
#define NODES_PER_BLOCK 4

typedef __attribute__((ext_vector_type(8))) short short8;
typedef __attribute__((ext_vector_type(4))) float f32x4;

__device__ __forceinline__ unsigned short f2bf(float f) {
    unsigned int u = __float_as_uint(f);
    unsigned int r = (u + 0x7fffu + ((u >> 16) & 1u)) >> 16;   // RNE
    return (unsigned short)r;
}
__device__ __forceinline__ float bf_lo(unsigned int u) { return __uint_as_float(u << 16); }
__device__ __forceinline__ float bf_hi(unsigned int u) { return __uint_as_float(u & 0xffff0000u); }
__device__ __forceinline__ float bfu(unsigned short u) { return __uint_as_float((unsigned int)u << 16); }

// ---------------- fused prep (96 blocks) + XCD-partitioned CSR fill ----------------
// prep: W1T[c][k]=bf16(W1[k][c]); W2T[c][k]=bf16(c<32 ? Wmu[k][c] : Wls[k][c-32]).
// fill: blocks round-robin XCDs (bid&7); group g commits only dst in [g*rng,(g+1)*rng) so each
// edge row is written from ONE XCD (no L2 line bouncing; ~deg x writeback -> 1x). Each group
// streams the whole edge list (L3 absorbs the 8x re-read). NB_P=96 ≡ 0 mod 8 keeps phase.
__global__ __launch_bounds__(256) void prep_fill_kernel(
    const float* __restrict__ W1, const float* __restrict__ Wmu, const float* __restrict__ Wls,
    unsigned short* __restrict__ W1T, unsigned short* __restrict__ W2T,
    const int* __restrict__ e1, const int* __restrict__ e2,
    int* __restrict__ counts, unsigned short* __restrict__ edges,
    int E1, int E2, int rng, int nbp) {
    int bid = blockIdx.x;
    if (bid < nbp) {                                   // ---- weight transpose path
        int idx = bid * 256 + threadIdx.x;
        if (idx < 128 * 128) {
            int c = idx >> 7, k = idx & 127;
            W1T[c * 128 + k] = f2bf(W1[k * 128 + c]);
        } else {
            int i2 = idx - 128 * 128;
            if (i2 < 64 * 128) {
                int c = i2 >> 7, k = i2 & 127;
                float v = (c < 32) ? Wmu[k * 32 + c] : Wls[k * 32 + (c - 32)];
                W2T[c * 128 + k] = f2bf(v);
            }
        }
        return;
    }
    // ---- CSR fill path
    int g  = bid & 7;                                  // XCD group (96 ≡ 0 mod 8)
    int lo = g * rng, hi = lo + rng;
    int base = ((bid - nbp) >> 3) * 2048;
#pragma unroll
    for (int i = 0; i < 8; ++i) {
        int e = base + i * 256 + threadIdx.x;
        int s, d;
        if (e < E1) {
            s = e1[e]; d = e1[E1 + e];
        } else if (e < E1 + E2) {
            int t = e - E1;
            s = e2[t]; d = e2[E2 + t];
        } else continue;
        if (d >= lo && d < hi) {
            int pos = atomicAdd(&counts[d], 1);
            if (pos < CAP) edges[d * CAP + pos] = (unsigned short)s;  // deg>CAP ~impossible
        }
    }
}

// ---------------- GEMM1 wave-strip: h1 = bf16( rsqrt(deg+1) * (x @ W1) ), LDS-free ----------
__global__ __launch_bounds__(256) void gemm1_kernel(
    const float* __restrict__ x, const unsigned short* __restrict__ W1T,
    const int* __restrict__ counts, unsigned short* __restrict__ h1, int M) {
    int wv = (blockIdx.x << 2) | (threadIdx.x >> 6);
    int brow = wv << 4;
    if (brow >= M) return;
    int lane = threadIdx.x & 63;
    int r = lane & 15, g = lane >> 4;
    const float* ar = x + (size_t)(brow + r) * 128;
    f32x4 acc[8] = {};
#pragma unroll
    for (int kk = 0; kk < 4; ++kk) {
        float4 a0 = *(const float4*)(ar + kk * 32 + g * 8);
        float4 a1 = *(const float4*)(ar + kk * 32 + g * 8 + 4);
        short8 af;
        af[0] = (short)f2bf(a0.x); af[1] = (short)f2bf(a0.y);
        af[2] = (short)f2bf(a0.z); af[3] = (short)f2bf(a0.w);
        af[4] = (short)f2bf(a1.x); af[5] = (short)f2bf(a1.y);
        af[6] = (short)f2bf(a1.z); af[7] = (short)f2bf(a1.w);
#pragma unroll
        for (int ct = 0; ct < 8; ++ct) {
            short8 b = *(const short8*)(W1T + (size_t)(ct * 16 + r) * 128 + kk * 32 + g * 8);
            acc[ct] = __builtin_amdgcn_mfma_f32_16x16x32_bf16(af, b, acc[ct], 0, 0, 0);
        }
    }
#pragma unroll
    for (int ct = 0; ct < 8; ++ct) {
#pragma unroll
        for (int rr = 0; rr < 4; ++rr) {
            int row = brow + 4 * g + rr;                 // C/D: col=lane&15, row=4*(lane>>4)+reg
            float sc = rsqrtf((float)(counts[row] + 1));
            h1[(size_t)row * 128 + ct * 16 + r] = f2bf(sc * acc[ct][rr]);
        }
    }
}

// ------- fused agg layer1 + GEMM2: h-row kept in LDS (fp32), g2 = bf16(dinv*(h @ W2)) -------
// Phase 1 (per wave = one node): ax,ay = sum of pre-scaled h1 rows; h_row = relu(di*sum + b1).
// Phase 2: lane c computes g2[v][c] = di * dot(h_row, W2T[c][:]) via 128-step VALU fma
// (W2T is 16KB, L1-resident; h_row via LDS broadcast reads). Saves h materialization entirely.
__global__ __launch_bounds__(256) void agg_h_g2_kernel(
    const unsigned short* __restrict__ h1, const unsigned short* __restrict__ edges,
    const int* __restrict__ counts, const float* __restrict__ b1,
    const unsigned short* __restrict__ W2T, unsigned short* __restrict__ g2, int n) {
    __shared__ float h_lds[NODES_PER_BLOCK][128];
    int wave = threadIdx.x >> 6, lane = threadIdx.x & 63;
    int v = blockIdx.x * NODES_PER_BLOCK + wave;
    bool active = v < n;
    float di = 0.f;
    if (active) {
        int cv = counts[v];
        int cnt = min(cv, CAP);
        di = rsqrtf((float)(cv + 1));
        const unsigned short* el = edges + (size_t)v * CAP;
        float ax = 0.f, ay = 0.f;
#pragma unroll 8
        for (int e = 0; e < cnt; ++e) {
            int s = el[e];
            unsigned int u = ((const unsigned int*)(h1 + (size_t)s * 128))[lane];
            ax += bf_lo(u);
            ay += bf_hi(u);
        }
        unsigned int su = ((const unsigned int*)(h1 + (size_t)v * 128))[lane];  // self (pre-scaled)
        ax += bf_lo(su);
        ay += bf_hi(su);
        h_lds[wave][2 * lane]     = fmaxf(di * ax + b1[2 * lane], 0.f);
        h_lds[wave][2 * lane + 1] = fmaxf(di * ay + b1[2 * lane + 1], 0.f);
    }
    __syncthreads();
    if (active) {
        const unsigned short* wrow = W2T + (size_t)lane * 128;   // lane = output col
        float acc = 0.f;
#pragma unroll
        for (int kk = 0; kk < 16; ++kk) {
            short8 wv8 = *(const short8*)(wrow + kk * 8);
#pragma unroll
            for (int j = 0; j < 8; ++j)
                acc = fmaf(h_lds[wave][kk * 8 + j], bfu((unsigned short)wv8[j]), acc);
        }
        g2[(size_t)v * 64 + lane] = f2bf(di * acc);
    }
}

// ---------------- agg layers 2+3: sum of pre-scaled g2 -> z_mu | z_logstd (fp32) -------------
__global__ void agg_out_kernel(const unsigned short* __restrict__ g,
                               const unsigned short* __restrict__ edges,
                               const int* __restrict__ counts,
                               const float* __restrict__ bmu, const float* __restrict__ bls,
                               float* __restrict__ out, int n) {
    int wave = threadIdx.x >> 6, lane = threadIdx.x & 63;
    int v = blockIdx.x * NODES_PER_BLOCK + wave;
    if (v >= n) return;
    int cv = counts[v];
    int cnt = min(cv, CAP);
    const unsigned short* el = edges + (size_t)v * CAP;
    float acc = 0.f;
#pragma unroll 8
    for (int e = 0; e < cnt; ++e) {
        int s = el[e];
        acc += bfu(g[(size_t)s * 64 + lane]);
    }
    acc += bfu(g[(size_t)v * 64 + lane]);   // self loop (pre-scaled)
    float res = rsqrtf((float)(cv + 1)) * acc;
    if (lane < 32) {
        out[(size_t)v * 32 + lane] = res + bmu[lane];
    } else {
        out[(size_t)n * 32 + (size_t)v * 32 + (lane - 32)] = res + bls[lane - 32];
    }
}

extern "C" void kernel_launch(void* const* d_in, const int* in_sizes, int n_in,
                              void* d_out, int out_size, void* d_ws, size_t ws_size,
                              hipStream_t stream) {
    const float* x   = (const float*)d_in[0];
    const int*   ei  = (const int*)d_in[1];   // int32 (harness delivers integer inputs as int32)
    const int*   yei = (const int*)d_in[2];
    const float* W1  = (const float*)d_in[3];
    const float* b1  = (const float*)d_in[4];
    const float* Wmu = (const float*)d_in[5];
    const float* bmu = (const float*)d_in[6];
    const float* Wls = (const float*)d_in[7];
    const float* bls = (const float*)d_in[8];

    const int N  = in_sizes[0] / 128;   // 50000
    const int E1 = in_sizes[1] / 2;     // 600000
    const int E2 = in_sizes[2] / 2;     // 200000
    const int E  = E1 + E2;             // 800000

    size_t off = 0;
    auto alloc = [&](size_t bytes) {
        char* p = (char*)d_ws + off;
        off += (bytes + 255) & ~(size_t)255;
        return (void*)p;
    };
    int*            counts = (int*)alloc((size_t)N * 4);
    unsigned short* edges  = (unsigned short*)alloc((size_t)N * CAP * 2);  // 6.4 MB
    unsigned short* h1     = (unsigned short*)alloc((size_t)N * 128 * 2);  // bf16, pre-scaled
    unsigned short* g2     = (unsigned short*)alloc((size_t)N * 64 * 2);   // bf16, pre-scaled
    unsigned short* W1T    = (unsigned short*)alloc(128 * 128 * 2);
    unsigned short* W2T    = (unsigned short*)alloc(64 * 128 * 2);
    (void)ws_size; (void)n_in; (void)out_size;

    const int NB_P  = (128 * 128 + 64 * 128) / 256;   // 96 prep blocks (≡ 0 mod 8)
    const int NB_C  = (E + 2047) / 2048;              // 391 fill chunks
    const int NB_G  = (N / 16 + 3) / 4;               // 782 wave-strip blocks
    const int NB_AG = (N + NODES_PER_BLOCK - 1) / NODES_PER_BLOCK;
    const int rng   = (N + 7) / 8;                    // dst range per XCD group

    hipMemsetAsync(counts, 0, (size_t)N * 4, stream);

    // weight transpose (96 blocks) || XCD-partitioned CSR fill (8 x 391 blocks)
    prep_fill_kernel<<<NB_P + 8 * NB_C, 256, 0, stream>>>(W1, Wmu, Wls, W1T, W2T,
                                                          ei, yei, counts, edges, E1, E2,
                                                          rng, NB_P);

    // h1 = bf16(dinv * (x @ W1))
    gemm1_kernel<<<NB_G, 256, 0, stream>>>(x, W1T, counts, h1, N);

    // h-row (fp32, LDS) = relu(dinv_v * sum + b1) ; g2 = bf16(dinv_v * (h @ [Wmu|Wls]))
    agg_h_g2_kernel<<<NB_AG, 64 * NODES_PER_BLOCK, 0, stream>>>(h1, edges, counts, b1, W2T, g2, N);

    // out = dinv_v * (sum g2) + bias
    agg_out_kernel<<<NB_AG, 64 * NODES_PER_BLOCK, 0, stream>>>(g2, edges, counts, bmu, bls,
                                                               (float*)d_out, N);
}

// Round 12
// 229.057 us; speedup vs baseline: 1.2888x; 1.2888x over previous
//
#include <hip/hip_runtime.h>
#include <hip/hip_bf16.h>

#define CAP 64
#define NODES_PER_BLOCK 4

typedef __attribute__((ext_vector_type(8))) short short8;
typedef __attribute__((ext_vector_type(4))) float f32x4;

__device__ __forceinline__ unsigned short f2bf(float f) {
    unsigned int u = __float_as_uint(f);
    unsigned int r = (u + 0x7fffu + ((u >> 16) & 1u)) >> 16;   // RNE
    return (unsigned short)r;
}
__device__ __forceinline__ float bf_lo(unsigned int u) { return __uint_as_float(u << 16); }
__device__ __forceinline__ float bf_hi(unsigned int u) { return __uint_as_float(u & 0xffff0000u); }
__device__ __forceinline__ float bfu(unsigned short u) { return __uint_as_float((unsigned int)u << 16); }

// ---------------- fused prep (96 blocks) + XCD-partitioned CSR fill ----------------
// prep: W1T[c][k]=bf16(W1[k][c]); W2T[c][k]=bf16(c<32 ? Wmu[k][c] : Wls[k][c-32]).
// fill: blocks round-robin XCDs (bid&7); group g commits only dst in [g*rng,(g+1)*rng) so each
// edge row is written from ONE XCD (no L2 line bouncing). NB_P=96 ≡ 0 mod 8 keeps phase.
__global__ __launch_bounds__(256) void prep_fill_kernel(
    const float* __restrict__ W1, const float* __restrict__ Wmu, const float* __restrict__ Wls,
    unsigned short* __restrict__ W1T, unsigned short* __restrict__ W2T,
    const int* __restrict__ e1, const int* __restrict__ e2,
    int* __restrict__ counts, unsigned short* __restrict__ edges,
    int E1, int E2, int rng, int nbp) {
    int bid = blockIdx.x;
    if (bid < nbp) {                                   // ---- weight transpose path
        int idx = bid * 256 + threadIdx.x;
        if (idx < 128 * 128) {
            int c = idx >> 7, k = idx & 127;
            W1T[c * 128 + k] = f2bf(W1[k * 128 + c]);
        } else {
            int i2 = idx - 128 * 128;
            if (i2 < 64 * 128) {
                int c = i2 >> 7, k = i2 & 127;
                float v = (c < 32) ? Wmu[k * 32 + c] : Wls[k * 32 + (c - 32)];
                W2T[c * 128 + k] = f2bf(v);
            }
        }
        return;
    }
    // ---- CSR fill path
    int g  = bid & 7;                                  // XCD group (96 ≡ 0 mod 8)
    int lo = g * rng, hi = lo + rng;
    int base = ((bid - nbp) >> 3) * 2048;
#pragma unroll
    for (int i = 0; i < 8; ++i) {
        int e = base + i * 256 + threadIdx.x;
        int s, d;
        if (e < E1) {
            s = e1[e]; d = e1[E1 + e];
        } else if (e < E1 + E2) {
            int t = e - E1;
            s = e2[t]; d = e2[E2 + t];
        } else continue;
        if (d >= lo && d < hi) {
            int pos = atomicAdd(&counts[d], 1);
            if (pos < CAP) edges[d * CAP + pos] = (unsigned short)s;  // deg>CAP ~impossible
        }
    }
}

// ---------------- GEMM1 wave-strip: h1 = bf16( rsqrt(deg+1) * (x @ W1) ), LDS-free ----------
__global__ __launch_bounds__(256) void gemm1_kernel(
    const float* __restrict__ x, const unsigned short* __restrict__ W1T,
    const int* __restrict__ counts, unsigned short* __restrict__ h1, int M) {
    int wv = (blockIdx.x << 2) | (threadIdx.x >> 6);
    int brow = wv << 4;
    if (brow >= M) return;
    int lane = threadIdx.x & 63;
    int r = lane & 15, g = lane >> 4;
    const float* ar = x + (size_t)(brow + r) * 128;
    f32x4 acc[8] = {};
#pragma unroll
    for (int kk = 0; kk < 4; ++kk) {
        float4 a0 = *(const float4*)(ar + kk * 32 + g * 8);
        float4 a1 = *(const float4*)(ar + kk * 32 + g * 8 + 4);
        short8 af;
        af[0] = (short)f2bf(a0.x); af[1] = (short)f2bf(a0.y);
        af[2] = (short)f2bf(a0.z); af[3] = (short)f2bf(a0.w);
        af[4] = (short)f2bf(a1.x); af[5] = (short)f2bf(a1.y);
        af[6] = (short)f2bf(a1.z); af[7] = (short)f2bf(a1.w);
#pragma unroll
        for (int ct = 0; ct < 8; ++ct) {
            short8 b = *(const short8*)(W1T + (size_t)(ct * 16 + r) * 128 + kk * 32 + g * 8);
            acc[ct] = __builtin_amdgcn_mfma_f32_16x16x32_bf16(af, b, acc[ct], 0, 0, 0);
        }
    }
#pragma unroll
    for (int ct = 0; ct < 8; ++ct) {
#pragma unroll
        for (int rr = 0; rr < 4; ++rr) {
            int row = brow + 4 * g + rr;                 // C/D: col=lane&15, row=4*(lane>>4)+reg
            float sc = rsqrtf((float)(counts[row] + 1));
            h1[(size_t)row * 128 + ct * 16 + r] = f2bf(sc * acc[ct][rr]);
        }
    }
}

// ---------------- agg layer 1: sum of pre-scaled h1 rows, x dinv_v, +b1, relu, bf16 ---------
__global__ void agg_h_kernel(const unsigned short* __restrict__ h1,
                             const unsigned short* __restrict__ edges,
                             const int* __restrict__ counts, const float* __restrict__ b1,
                             unsigned short* __restrict__ h, int n) {
    int wave = threadIdx.x >> 6, lane = threadIdx.x & 63;
    int v = blockIdx.x * NODES_PER_BLOCK + wave;
    if (v >= n) return;
    int cv = counts[v];
    int cnt = min(cv, CAP);
    const unsigned short* el = edges + (size_t)v * CAP;
    float ax = 0.f, ay = 0.f;
#pragma unroll 8
    for (int e = 0; e < cnt; ++e) {
        int s = el[e];
        unsigned int u = ((const unsigned int*)(h1 + (size_t)s * 128))[lane];
        ax += bf_lo(u);
        ay += bf_hi(u);
    }
    unsigned int su = ((const unsigned int*)(h1 + (size_t)v * 128))[lane];  // self (pre-scaled)
    ax += bf_lo(su);
    ay += bf_hi(su);
    float di = rsqrtf((float)(cv + 1));
    float ox = di * ax + b1[2 * lane];
    float oy = di * ay + b1[2 * lane + 1];
    unsigned int pack = (unsigned int)f2bf(fmaxf(ox, 0.f)) |
                        ((unsigned int)f2bf(fmaxf(oy, 0.f)) << 16);
    ((unsigned int*)(h + (size_t)v * 128))[lane] = pack;
}

// ---------------- GEMM2 wave-strip: g2 = bf16( rsqrt(deg+1) * (h @ [Wmu|Wls]) ) -------------
__global__ __launch_bounds__(256) void gemm2_kernel(const unsigned short* __restrict__ h,
                                                    const unsigned short* __restrict__ W2T,
                                                    const int* __restrict__ counts,
                                                    unsigned short* __restrict__ g2, int M) {
    int wv = (blockIdx.x << 2) | (threadIdx.x >> 6);
    int brow = wv << 4;
    if (brow >= M) return;
    int lane = threadIdx.x & 63;
    int r = lane & 15, g = lane >> 4;
    const unsigned short* ar = h + (size_t)(brow + r) * 128;
    f32x4 acc[4] = {};
#pragma unroll
    for (int kk = 0; kk < 4; ++kk) {
        short8 af = *(const short8*)(ar + kk * 32 + g * 8);
#pragma unroll
        for (int ct = 0; ct < 4; ++ct) {
            short8 b = *(const short8*)(W2T + (size_t)(ct * 16 + r) * 128 + kk * 32 + g * 8);
            acc[ct] = __builtin_amdgcn_mfma_f32_16x16x32_bf16(af, b, acc[ct], 0, 0, 0);
        }
    }
#pragma unroll
    for (int ct = 0; ct < 4; ++ct) {
#pragma unroll
        for (int rr = 0; rr < 4; ++rr) {
            int row = brow + 4 * g + rr;
            float sc = rsqrtf((float)(counts[row] + 1));
            g2[(size_t)row * 64 + ct * 16 + r] = f2bf(sc * acc[ct][rr]);
        }
    }
}

// ---------------- agg layers 2+3: sum of pre-scaled g2 -> z_mu | z_logstd (fp32) -------------
__global__ void agg_out_kernel(const unsigned short* __restrict__ g,
                               const unsigned short* __restrict__ edges,
                               const int* __restrict__ counts,
                               const float* __restrict__ bmu, const float* __restrict__ bls,
                               float* __restrict__ out, int n) {
    int wave = threadIdx.x >> 6, lane = threadIdx.x & 63;
    int v = blockIdx.x * NODES_PER_BLOCK + wave;
    if (v >= n) return;
    int cv = counts[v];
    int cnt = min(cv, CAP);
    const unsigned short* el = edges + (size_t)v * CAP;
    float acc = 0.f;
#pragma unroll 8
    for (int e = 0; e < cnt; ++e) {
        int s = el[e];
        acc += bfu(g[(size_t)s * 64 + lane]);
    }
    acc += bfu(g[(size_t)v * 64 + lane]);   // self loop (pre-scaled)
    float res = rsqrtf((float)(cv + 1)) * acc;
    if (lane < 32) {
        out[(size_t)v * 32 + lane] = res + bmu[lane];
    } else {
        out[(size_t)n * 32 + (size_t)v * 32 + (lane - 32)] = res + bls[lane - 32];
    }
}

extern "C" void kernel_launch(void* const* d_in, const int* in_sizes, int n_in,
                              void* d_out, int out_size, void* d_ws, size_t ws_size,
                              hipStream_t stream) {
    const float* x   = (const float*)d_in[0];
    const int*   ei  = (const int*)d_in[1];   // int32 (harness delivers integer inputs as int32)
    const int*   yei = (const int*)d_in[2];
    const float* W1  = (const float*)d_in[3];
    const float* b1  = (const float*)d_in[4];
    const float* Wmu = (const float*)d_in[5];
    const float* bmu = (const float*)d_in[6];
    const float* Wls = (const float*)d_in[7];
    const float* bls = (const float*)d_in[8];

    const int N  = in_sizes[0] / 128;   // 50000
    const int E1 = in_sizes[1] / 2;     // 600000
    const int E2 = in_sizes[2] / 2;     // 200000
    const int E  = E1 + E2;             // 800000

    size_t off = 0;
    auto alloc = [&](size_t bytes) {
        char* p = (char*)d_ws + off;
        off += (bytes + 255) & ~(size_t)255;
        return (void*)p;
    };
    int*            counts = (int*)alloc((size_t)N * 4);
    unsigned short* edges  = (unsigned short*)alloc((size_t)N * CAP * 2);  // 6.4 MB
    unsigned short* h1     = (unsigned short*)alloc((size_t)N * 128 * 2);  // bf16, pre-scaled
    unsigned short* h      = (unsigned short*)alloc((size_t)N * 128 * 2);  // bf16
    unsigned short* g2     = (unsigned short*)alloc((size_t)N * 64 * 2);   // bf16, pre-scaled
    unsigned short* W1T    = (unsigned short*)alloc(128 * 128 * 2);
    unsigned short* W2T    = (unsigned short*)alloc(64 * 128 * 2);
    (void)ws_size; (void)n_in; (void)out_size;

    const int NB_P  = (128 * 128 + 64 * 128) / 256;   // 96 prep blocks (≡ 0 mod 8)
    const int NB_C  = (E + 2047) / 2048;              // 391 fill chunks
    const int NB_G  = (N / 16 + 3) / 4;               // 782 wave-strip blocks
    const int NB_AG = (N + NODES_PER_BLOCK - 1) / NODES_PER_BLOCK;
    const int rng   = (N + 7) / 8;                    // dst range per XCD group

    hipMemsetAsync(counts, 0, (size_t)N * 4, stream);

    // weight transpose (96 blocks) || XCD-partitioned CSR fill (8 x 391 blocks)
    prep_fill_kernel<<<NB_P + 8 * NB_C, 256, 0, stream>>>(W1, Wmu, Wls, W1T, W2T,
                                                          ei, yei, counts, edges, E1, E2,
                                                          rng, NB_P);

    // h1 = bf16(dinv * (x @ W1))
    gemm1_kernel<<<NB_G, 256, 0, stream>>>(x, W1T, counts, h1, N);

    // h = bf16(relu(dinv_v * sum + b1))
    agg_h_kernel<<<NB_AG, 64 * NODES_PER_BLOCK, 0, stream>>>(h1, edges, counts, b1, h, N);

    // g2 = bf16(dinv * (h @ [Wmu|Wls]))
    gemm2_kernel<<<NB_G, 256, 0, stream>>>(h, W2T, counts, g2, N);

    // out = dinv_v * (sum g2) + bias
    agg_out_kernel<<<NB_AG, 64 * NODES_PER_BLOCK, 0, stream>>>(g2, edges, counts, bmu, bls,
                                                               (float*)d_out, N);
}